// Round 2
// baseline (552.244 us; speedup 1.0000x reference)
//
#include <hip/hip_runtime.h>
#include <cmath>

// Bahdanau attention, MI355X. B=32, T=8192, D=256, U=128, fp32.
// Round 5: occupancy fix. R4 decomposition: 392us total = ~320us harness
// 1-GiB ws-poison fills (invariant) + ~62us score_ctx + ~10us prep/epilogue;
// score_ctx floor is ~43us (268MB values @6.3TB/s).
// Bug: __launch_bounds__(512,2) = 2 waves/EU = exactly one 512-thr block ->
// allocator free up to 256 VGPR -> 1 block/CU resident (LDS 67.6KB would
// allow 2). With 1 block/CU the per-half 32KB HBM burst (~3100cyc at the
// 24.6GB/s per-CU share) can't hide under ~1200cyc of compute -> ~2000cyc
// stall per half at the pre-stage_store vmcnt wait.
// Fix: __launch_bounds__(512,4) caps VGPR at 128 -> 2 resident blocks ->
// cross-block overlap of HBM bursts with MFMA/epilogue phases.
// Persistent regs ~80 (64 B-frag + 16 stage) + transients ~30 -> fits 128.
// Fallback if this spills (scratch traffic, dur regression): split B-frag
// ownership across 2 half-blocks of 256 threads.

#define B_ 32
#define T_ 8192
#define D_ 256
#define U_ 128
#define NBC_ 32            // blocks per batch, 256 rows each
#define GRP_ 520           // ushort stride per (mt,kk) tile: 64*8 + 8 pad

typedef float f32x4 __attribute__((ext_vector_type(4)));
typedef short s16x8 __attribute__((ext_vector_type(8)));
typedef __bf16 bf16x8 __attribute__((ext_vector_type(8)));

// tanh(x) = 1 - 2/(e^2x + 1); exact limits, ~1e-7 rel err, no NaN.
__device__ __forceinline__ float tanh_fast(float x) {
    float e = __expf(2.f * x);
    return 1.f - 2.f * __builtin_amdgcn_rcpf(e + 1.f);
}

// ---------------- k0: prep W1 frags (blocks 0..127) + hq (blocks 128..159) --
// W1 frag element idx = ((kk*8+nn)*64 + lane)*8 + j
//   <-> W1[k][n], k = kk*32 + (lane>>4)*8 + j, n = nn*16 + (lane&15)
__global__ __launch_bounds__(256) void prep(
    const float* __restrict__ W1, const float* __restrict__ query,
    const float* __restrict__ W2, const float* __restrict__ b2,
    unsigned short* __restrict__ W1h, unsigned short* __restrict__ W1l,
    float* __restrict__ hq)
{
    int blk = blockIdx.x, tid = threadIdx.x;
    if (blk < 128) {
        int idx2 = blk * 256 + tid;          // coalesced W1 read
        int k = idx2 >> 7, n = idx2 & 127;
        float wv = W1[idx2];
        int kk = k >> 5, j = k & 7, lg = (k >> 3) & 3;
        int lane = lg * 16 + (n & 15);
        int nn = n >> 4;
        int pos = ((kk * 8 + nn) * 64 + lane) * 8 + j;
        __bf16 hb = (__bf16)wv;
        float hf = (float)hb;
        __bf16 lb = (__bf16)(wv - hf);
        W1h[pos] = __builtin_bit_cast(unsigned short, hb);
        W1l[pos] = __builtin_bit_cast(unsigned short, lb);
    } else {
        __shared__ float hq2[256];
        int b = blk - 128;
        int u = tid & 127, half = tid >> 7;
        float acc = half ? 0.f : b2[u];
        const float* q = query + b * D_ + half * 128;
        const float* w2 = W2 + (half * 128) * U_ + u;
        for (int d = 0; d < 128; ++d)
            acc = fmaf(q[d], w2[d * U_], acc);
        hq2[tid] = acc;
        __syncthreads();
        if (tid < 128) hq[b * U_ + tid] = fmaxf(hq2[tid] + hq2[tid + 128], 0.f);
    }
}

// ---------------- k1: fused scores + exp + partial context -----------------
// stage split (T14): load global -> regs early; convert + LDS write late.
__device__ __forceinline__ void stage_load(
    const float* __restrict__ src, int w, int lane, float4 xr[2][2])
{
#pragma unroll
    for (int p = 0; p < 2; ++p) {
        int tile = w * 2 + p;                // 0..15
        int mt = tile >> 3, kk = tile & 7;
        const float* ptr = src + (mt * 16 + (lane & 15)) * D_ + kk * 32 + (lane >> 4) * 8;
        xr[p][0] = *(const float4*)ptr;
        xr[p][1] = *(const float4*)(ptr + 4);
    }
}

__device__ __forceinline__ void stage_store(
    int w, int lane, const float4 xr[2][2],
    unsigned short* __restrict__ Ah, unsigned short* __restrict__ Al)
{
#pragma unroll
    for (int p = 0; p < 2; ++p) {
        int tile = w * 2 + p;
        int mt = tile >> 3, kk = tile & 7;
        float xs[8] = {xr[p][0].x, xr[p][0].y, xr[p][0].z, xr[p][0].w,
                       xr[p][1].x, xr[p][1].y, xr[p][1].z, xr[p][1].w};
        s16x8 hv, lv;
#pragma unroll
        for (int e = 0; e < 8; ++e) {
            __bf16 hb = (__bf16)xs[e];
            float hf = (float)hb;
            __bf16 lb = (__bf16)(xs[e] - hf);
            hv[e] = __builtin_bit_cast(short, hb);
            lv[e] = __builtin_bit_cast(short, lb);
        }
        int off = (mt * 8 + kk) * GRP_ + lane * 8;   // lane*16B: conflict-free
        *(s16x8*)&Ah[off] = hv;
        *(s16x8*)&Al[off] = lv;
    }
}

__global__ __launch_bounds__(512, 4) void score_ctx(
    const float* __restrict__ values,
    const unsigned short* __restrict__ W1h, const unsigned short* __restrict__ W1l,
    const float* __restrict__ hq, const float* __restrict__ b1,
    const float* __restrict__ Vk,
    float* __restrict__ sc_g, float* __restrict__ st_g, float* __restrict__ cp_g)
{
    __shared__ __align__(16) unsigned short AhB[2][16 * GRP_];   // 2 x 16640 B
    __shared__ __align__(16) unsigned short AlB[2][16 * GRP_];   // 2 x 16640 B
    __shared__ float scp[8][32];
    __shared__ float esc[32];
    __shared__ float cbuf[256];

    const int tid = threadIdx.x;
    const int b = blockIdx.x >> 5;       // NBC_=32 blocks per batch
    const int blkc = blockIdx.x & 31;
    const int lane = tid & 63;
    const int w = tid >> 6;              // 8 waves; wave w owns unit tile nn=w
    const int u0 = lane & 15;

    // ---- B frags register-resident: loaded once per block ----
    bf16x8 bfh[8], bfl[8];
#pragma unroll
    for (int kk = 0; kk < 8; ++kk) {
        int boff = ((kk * 8 + w) * 64 + lane) * 8;
        bfh[kk] = __builtin_bit_cast(bf16x8, *(const s16x8*)&W1h[boff]);
        bfl[kk] = __builtin_bit_cast(bf16x8, *(const s16x8*)&W1l[boff]);
    }

    const int u = w * 16 + u0;
    const float b1v = b1[u];
    const float hqv = hq[b * U_ + u];
    const float Vv = Vk[u];

    float l_acc = 0.f;                   // thread 0 only (sum of exp)
    float c1 = 0.f;                      // per-thread ctx partial
    const int tb = blkc * 256;
    const float* vblk = values + ((size_t)b * T_ + tb) * D_;

    float4 xr[2][2];
    stage_load(vblk, w, lane, xr);
    stage_store(w, lane, xr, AhB[0], AlB[0]);
    int cur = 0;

#pragma unroll 2
    for (int hh = 0; hh < 8; ++hh) {     // 8 halves of 32 rows
        __syncthreads();                 // buf[cur] staged by all waves

        // issue next half's global loads early (latency hides under MFMA)
        if (hh < 7) stage_load(vblk + (size_t)(hh + 1) * 32 * D_, w, lane, xr);

        // ---- MFMA: wave w, unit tile nn=w, row tiles mt=0,1 ----
        const unsigned short* Ah = AhB[cur];
        const unsigned short* Al = AlB[cur];
        f32x4 acc[2];
        acc[0] = (f32x4){0.f, 0.f, 0.f, 0.f};
        acc[1] = (f32x4){0.f, 0.f, 0.f, 0.f};
#pragma unroll
        for (int kk = 0; kk < 8; ++kk) {
#pragma unroll
            for (int mt = 0; mt < 2; ++mt) {
                int aoff = (mt * 8 + kk) * GRP_ + lane * 8;
                bf16x8 ah = __builtin_bit_cast(bf16x8, *(const s16x8*)&Ah[aoff]);
                bf16x8 al = __builtin_bit_cast(bf16x8, *(const s16x8*)&Al[aoff]);
                acc[mt] = __builtin_amdgcn_mfma_f32_16x16x32_bf16(ah, bfh[kk], acc[mt], 0, 0, 0);
                acc[mt] = __builtin_amdgcn_mfma_f32_16x16x32_bf16(ah, bfl[kk], acc[mt], 0, 0, 0);
                acc[mt] = __builtin_amdgcn_mfma_f32_16x16x32_bf16(al, bfh[kk], acc[mt], 0, 0, 0);
            }
        }

        // ---- per-wave partial scores over its 16 units ----
#pragma unroll
        for (int mt = 0; mt < 2; ++mt) {
            float p[4];
#pragma unroll
            for (int i = 0; i < 4; ++i) {
                float hpre = fmaxf(acc[mt][i] + b1v, 0.f) + hqv;
                p[i] = tanh_fast(hpre) * Vv;
            }
#pragma unroll
            for (int off = 1; off < 16; off <<= 1)
#pragma unroll
                for (int i = 0; i < 4; ++i) p[i] += __shfl_xor(p[i], off, 16);
            if (u0 == 0) {
                int base = mt * 16 + (lane >> 4) * 4;
#pragma unroll
                for (int i = 0; i < 4; ++i) scp[w][base + i] = p[i];
            }
        }
        __syncthreads();

        // ---- no-max softmax: |s| <= sum|Vk| ~ 5.1, exp(s) safe ----
        if (tid < 32) {
            float s = 0.f;
#pragma unroll
            for (int ww = 0; ww < 8; ++ww) s += scp[ww][tid];
            sc_g[(size_t)b * T_ + tb + hh * 32 + tid] = s;
            float e = __expf(s);
            esc[tid] = e;
            float lh = e;
#pragma unroll
            for (int off = 16; off >= 1; off >>= 1)
                lh += __shfl_xor(lh, off, 32);
            if (tid == 0) l_acc += lh;
        }
        __syncthreads();

        // ---- ctx accumulate from global (L1/L2-hot), coalesced ----
        {
            int colr = tid & 255, rh = tid >> 8;    // 2 row-groups of 16
            const float* vcol = vblk + (size_t)(hh * 32 + rh * 16) * D_ + colr;
#pragma unroll
            for (int tl = 0; tl < 16; ++tl)
                c1 = fmaf(esc[rh * 16 + tl], vcol[(size_t)tl * D_], c1);
        }

        // convert + LDS-write next half (loads have landed by now)
        if (hh < 7) stage_store(w, lane, xr, AhB[cur ^ 1], AlB[cur ^ 1]);
        cur ^= 1;
    }

    // ---- block tail: combine the two row-group ctx partials ----
    if (tid >= 256) cbuf[tid - 256] = c1;
    __syncthreads();
    if (tid < 256)
        cp_g[((size_t)(b * NBC_ + blkc)) * D_ + tid] = c1 + cbuf[tid];
    if (tid == 0) st_g[b * NBC_ + blkc] = l_acc;
}

// ---------------- k2: epilogue — attn (blocks 0..255) + ctx (256..287) -----
__global__ __launch_bounds__(256) void epilogue(
    const float* __restrict__ sc_g, const float* __restrict__ st_g,
    const float* __restrict__ cp_g, float* __restrict__ out)
{
    __shared__ float invL_s;
    int blk = blockIdx.x, tid = threadIdx.x;
    int b = (blk < 256) ? (blk >> 3) : (blk - 256);

    if (tid < 32) {
        float l = st_g[b * NBC_ + tid];
#pragma unroll
        for (int off = 16; off >= 1; off >>= 1)
            l += __shfl_xor(l, off, 32);
        if (tid == 0) invL_s = 1.f / l;
    }
    __syncthreads();
    float invL = invL_s;

    if (blk < 256) {
        int s8 = blk & 7;
        int t = s8 * 1024 + tid * 4;
        float4 s4 = *(const float4*)&sc_g[(size_t)b * T_ + t];
        float4 r;
        r.x = __expf(s4.x) * invL;
        r.y = __expf(s4.y) * invL;
        r.z = __expf(s4.z) * invL;
        r.w = __expf(s4.w) * invL;
        *(float4*)&out[B_ * D_ + (size_t)b * T_ + t] = r;
    } else {
        float a = 0.f;
        const float* p = cp_g + (size_t)b * NBC_ * D_ + tid;
#pragma unroll 8
        for (int c2 = 0; c2 < NBC_; ++c2)
            a += p[(size_t)c2 * D_];
        out[b * D_ + tid] = a * invL;
    }
}

// ---------------- launch ----------------
extern "C" void kernel_launch(void* const* d_in, const int* in_sizes, int n_in,
                              void* d_out, int out_size, void* d_ws, size_t ws_size,
                              hipStream_t stream)
{
    const float* query = (const float*)d_in[0];
    const float* values = (const float*)d_in[1];
    const float* W1 = (const float*)d_in[2];
    const float* b1 = (const float*)d_in[3];
    const float* W2 = (const float*)d_in[4];
    const float* b2 = (const float*)d_in[5];
    const float* Vk = (const float*)d_in[6];
    // d_in[7] = V_bias: constant score shift, cancels in softmax.
    float* out = (float*)d_out;
    char* ws = (char*)d_ws;

    // ws layout (bytes), total 2,248,704
    float* scores = (float*)(ws + 0);                  // B*T*4        = 1048576
    float* hq     = (float*)(ws + 1048576);            // B*U*4        = 16384
    float* stats  = (float*)(ws + 1064960);            // B*32*4       = 4096
    float* ctxp   = (float*)(ws + 1069056);            // B*32*256*4   = 1048576
    unsigned short* W1h = (unsigned short*)(ws + 2117632);   // 65536
    unsigned short* W1l = (unsigned short*)(ws + 2183168);   // 65536

    prep<<<160, 256, 0, stream>>>(W1, query, W2, b2, W1h, W1l, hq);
    score_ctx<<<B_ * NBC_, 512, 0, stream>>>(values, W1h, W1l, hq, b1, Vk,
                                             scores, stats, ctxp);
    epilogue<<<288, 256, 0, stream>>>(scores, stats, ctxp, out);
}

// Round 4
// 389.589 us; speedup vs baseline: 1.4175x; 1.4175x over previous
//
#include <hip/hip_runtime.h>
#include <cmath>

// Bahdanau attention, MI355X. B=32, T=8192, D=256, U=128, fp32.
// Round 7 = Round 6 resubmit (R6 bench died on container acquisition, not the
// kernel: no pytest failure, push path showed 1800-2900s npz pushes).
// R6 change over R1 (391.8us): per-half softmax stats were computed by 32
// lanes of wave 0 while 7.5 waves idled at a barrier (3 barriers/half).
// Now every wave redundantly computes s/e from scp (broadcast LDS reads) and
// distributes e in-register via __shfl -> deletes 1 barrier/half + the
// serial section. Expected -5us; score_ctx ~55-58us vs 43us HBM floor.
// Known-bad alternatives (measured): launch_bounds(512,4) -> VGPR=64, 570MB
// spill traffic, score_ctx 273us (R5). Keep (512,2).

#define B_ 32
#define T_ 8192
#define D_ 256
#define U_ 128
#define NBC_ 32            // blocks per batch, 256 rows each
#define GRP_ 520           // ushort stride per (mt,kk) tile: 64*8 + 8 pad

typedef float f32x4 __attribute__((ext_vector_type(4)));
typedef short s16x8 __attribute__((ext_vector_type(8)));
typedef __bf16 bf16x8 __attribute__((ext_vector_type(8)));

// tanh(x) = 1 - 2/(e^2x + 1); exact limits, ~1e-7 rel err, no NaN.
__device__ __forceinline__ float tanh_fast(float x) {
    float e = __expf(2.f * x);
    return 1.f - 2.f * __builtin_amdgcn_rcpf(e + 1.f);
}

// ---------------- k0: prep W1 frags (blocks 0..127) + hq (blocks 128..159) --
// W1 frag element idx = ((kk*8+nn)*64 + lane)*8 + j
//   <-> W1[k][n], k = kk*32 + (lane>>4)*8 + j, n = nn*16 + (lane&15)
__global__ __launch_bounds__(256) void prep(
    const float* __restrict__ W1, const float* __restrict__ query,
    const float* __restrict__ W2, const float* __restrict__ b2,
    unsigned short* __restrict__ W1h, unsigned short* __restrict__ W1l,
    float* __restrict__ hq)
{
    int blk = blockIdx.x, tid = threadIdx.x;
    if (blk < 128) {
        int idx2 = blk * 256 + tid;          // coalesced W1 read
        int k = idx2 >> 7, n = idx2 & 127;
        float wv = W1[idx2];
        int kk = k >> 5, j = k & 7, lg = (k >> 3) & 3;
        int lane = lg * 16 + (n & 15);
        int nn = n >> 4;
        int pos = ((kk * 8 + nn) * 64 + lane) * 8 + j;
        __bf16 hb = (__bf16)wv;
        float hf = (float)hb;
        __bf16 lb = (__bf16)(wv - hf);
        W1h[pos] = __builtin_bit_cast(unsigned short, hb);
        W1l[pos] = __builtin_bit_cast(unsigned short, lb);
    } else {
        __shared__ float hq2[256];
        int b = blk - 128;
        int u = tid & 127, half = tid >> 7;
        float acc = half ? 0.f : b2[u];
        const float* q = query + b * D_ + half * 128;
        const float* w2 = W2 + (half * 128) * U_ + u;
        for (int d = 0; d < 128; ++d)
            acc = fmaf(q[d], w2[d * U_], acc);
        hq2[tid] = acc;
        __syncthreads();
        if (tid < 128) hq[b * U_ + tid] = fmaxf(hq2[tid] + hq2[tid + 128], 0.f);
    }
}

// ---------------- k1: fused scores + exp + partial context -----------------
// stage split (T14): load global -> regs early; convert + LDS write late.
__device__ __forceinline__ void stage_load(
    const float* __restrict__ src, int w, int lane, float4 xr[2][2])
{
#pragma unroll
    for (int p = 0; p < 2; ++p) {
        int tile = w * 2 + p;                // 0..15
        int mt = tile >> 3, kk = tile & 7;
        const float* ptr = src + (mt * 16 + (lane & 15)) * D_ + kk * 32 + (lane >> 4) * 8;
        xr[p][0] = *(const float4*)ptr;
        xr[p][1] = *(const float4*)(ptr + 4);
    }
}

__device__ __forceinline__ void stage_store(
    int w, int lane, const float4 xr[2][2],
    unsigned short* __restrict__ Ah, unsigned short* __restrict__ Al)
{
#pragma unroll
    for (int p = 0; p < 2; ++p) {
        int tile = w * 2 + p;
        int mt = tile >> 3, kk = tile & 7;
        float xs[8] = {xr[p][0].x, xr[p][0].y, xr[p][0].z, xr[p][0].w,
                       xr[p][1].x, xr[p][1].y, xr[p][1].z, xr[p][1].w};
        s16x8 hv, lv;
#pragma unroll
        for (int e = 0; e < 8; ++e) {
            __bf16 hb = (__bf16)xs[e];
            float hf = (float)hb;
            __bf16 lb = (__bf16)(xs[e] - hf);
            hv[e] = __builtin_bit_cast(short, hb);
            lv[e] = __builtin_bit_cast(short, lb);
        }
        int off = (mt * 8 + kk) * GRP_ + lane * 8;   // lane*16B: conflict-free
        *(s16x8*)&Ah[off] = hv;
        *(s16x8*)&Al[off] = lv;
    }
}

__global__ __launch_bounds__(512, 2) void score_ctx(
    const float* __restrict__ values,
    const unsigned short* __restrict__ W1h, const unsigned short* __restrict__ W1l,
    const float* __restrict__ hq, const float* __restrict__ b1,
    const float* __restrict__ Vk,
    float* __restrict__ sc_g, float* __restrict__ st_g, float* __restrict__ cp_g)
{
    __shared__ __align__(16) unsigned short AhB[2][16 * GRP_];   // 2 x 16640 B
    __shared__ __align__(16) unsigned short AlB[2][16 * GRP_];   // 2 x 16640 B
    __shared__ float scp[8][32];
    __shared__ float cbuf[256];

    const int tid = threadIdx.x;
    const int b = blockIdx.x >> 5;       // NBC_=32 blocks per batch
    const int blkc = blockIdx.x & 31;
    const int lane = tid & 63;
    const int w = tid >> 6;              // 8 waves; wave w owns unit tile nn=w
    const int u0 = lane & 15;

    // ---- B frags register-resident: loaded once per block ----
    bf16x8 bfh[8], bfl[8];
#pragma unroll
    for (int kk = 0; kk < 8; ++kk) {
        int boff = ((kk * 8 + w) * 64 + lane) * 8;
        bfh[kk] = __builtin_bit_cast(bf16x8, *(const s16x8*)&W1h[boff]);
        bfl[kk] = __builtin_bit_cast(bf16x8, *(const s16x8*)&W1l[boff]);
    }

    const int u = w * 16 + u0;
    const float b1v = b1[u];
    const float hqv = hq[b * U_ + u];
    const float Vv = Vk[u];

    float l_acc = 0.f;                   // lane 0 of wave 0 (sum of exp)
    float c1 = 0.f;                      // per-thread ctx partial
    const int tb = blkc * 256;
    const float* vblk = values + ((size_t)b * T_ + tb) * D_;

    float4 xr[2][2];
    stage_load(vblk, w, lane, xr);
    stage_store(w, lane, xr, AhB[0], AlB[0]);
    int cur = 0;

#pragma unroll 2
    for (int hh = 0; hh < 8; ++hh) {     // 8 halves of 32 rows
        __syncthreads();                 // buf[cur] staged by all waves

        // issue next half's global loads early (latency hides under MFMA)
        if (hh < 7) stage_load(vblk + (size_t)(hh + 1) * 32 * D_, w, lane, xr);

        // ---- MFMA: wave w, unit tile nn=w, row tiles mt=0,1 ----
        const unsigned short* Ah = AhB[cur];
        const unsigned short* Al = AlB[cur];
        f32x4 acc[2];
        acc[0] = (f32x4){0.f, 0.f, 0.f, 0.f};
        acc[1] = (f32x4){0.f, 0.f, 0.f, 0.f};
#pragma unroll
        for (int kk = 0; kk < 8; ++kk) {
#pragma unroll
            for (int mt = 0; mt < 2; ++mt) {
                int aoff = (mt * 8 + kk) * GRP_ + lane * 8;
                bf16x8 ah = __builtin_bit_cast(bf16x8, *(const s16x8*)&Ah[aoff]);
                bf16x8 al = __builtin_bit_cast(bf16x8, *(const s16x8*)&Al[aoff]);
                acc[mt] = __builtin_amdgcn_mfma_f32_16x16x32_bf16(ah, bfh[kk], acc[mt], 0, 0, 0);
                acc[mt] = __builtin_amdgcn_mfma_f32_16x16x32_bf16(ah, bfl[kk], acc[mt], 0, 0, 0);
                acc[mt] = __builtin_amdgcn_mfma_f32_16x16x32_bf16(al, bfh[kk], acc[mt], 0, 0, 0);
            }
        }

        // ---- per-wave partial scores over its 16 units ----
#pragma unroll
        for (int mt = 0; mt < 2; ++mt) {
            float p[4];
#pragma unroll
            for (int i = 0; i < 4; ++i) {
                float hpre = fmaxf(acc[mt][i] + b1v, 0.f) + hqv;
                p[i] = tanh_fast(hpre) * Vv;
            }
#pragma unroll
            for (int off = 1; off < 16; off <<= 1)
#pragma unroll
                for (int i = 0; i < 4; ++i) p[i] += __shfl_xor(p[i], off, 16);
            if (u0 == 0) {
                int base = mt * 16 + (lane >> 4) * 4;
#pragma unroll
                for (int i = 0; i < 4; ++i) scp[w][base + i] = p[i];
            }
        }
        __syncthreads();

        // ---- wave-redundant no-max softmax (|s| <= sum|Vk| ~5.1): every
        // wave computes e(t) for t=lane&31 (dup in upper half) from scp
        // broadcast reads; e distributed via shfl -> no barrier, no esc[] ----
        {
            int t = lane & 31;
            float s = 0.f;
#pragma unroll
            for (int ww = 0; ww < 8; ++ww) s += scp[ww][t];
            float e = __expf(s);
            if (w == 0 && lane < 32) {
                sc_g[(size_t)b * T_ + tb + hh * 32 + lane] = s;
                float lh = e;
#pragma unroll
                for (int off = 16; off >= 1; off >>= 1)
                    lh += __shfl_xor(lh, off, 32);
                if (lane == 0) l_acc += lh;
            }

            // ---- ctx accumulate from global (L2-hot), coalesced ----
            int colr = tid & 255, rh = tid >> 8;    // 2 row-groups of 16
            const float* vcol = vblk + (size_t)(hh * 32 + rh * 16) * D_ + colr;
#pragma unroll
            for (int tl = 0; tl < 16; ++tl)
                c1 = fmaf(__shfl(e, rh * 16 + tl, 64), vcol[(size_t)tl * D_], c1);
        }

        // convert + LDS-write next half (loads have landed by now)
        if (hh < 7) stage_store(w, lane, xr, AhB[cur ^ 1], AlB[cur ^ 1]);
        cur ^= 1;
    }

    // ---- block tail: combine the two row-group ctx partials ----
    if (tid >= 256) cbuf[tid - 256] = c1;
    __syncthreads();
    if (tid < 256)
        cp_g[((size_t)(b * NBC_ + blkc)) * D_ + tid] = c1 + cbuf[tid];
    if (tid == 0) st_g[b * NBC_ + blkc] = l_acc;
}

// ---------------- k2: epilogue — attn (blocks 0..255) + ctx (256..287) -----
__global__ __launch_bounds__(256) void epilogue(
    const float* __restrict__ sc_g, const float* __restrict__ st_g,
    const float* __restrict__ cp_g, float* __restrict__ out)
{
    __shared__ float invL_s;
    int blk = blockIdx.x, tid = threadIdx.x;
    int b = (blk < 256) ? (blk >> 3) : (blk - 256);

    if (tid < 32) {
        float l = st_g[b * NBC_ + tid];
#pragma unroll
        for (int off = 16; off >= 1; off >>= 1)
            l += __shfl_xor(l, off, 32);
        if (tid == 0) invL_s = 1.f / l;
    }
    __syncthreads();
    float invL = invL_s;

    if (blk < 256) {
        int s8 = blk & 7;
        int t = s8 * 1024 + tid * 4;
        float4 s4 = *(const float4*)&sc_g[(size_t)b * T_ + t];
        float4 r;
        r.x = __expf(s4.x) * invL;
        r.y = __expf(s4.y) * invL;
        r.z = __expf(s4.z) * invL;
        r.w = __expf(s4.w) * invL;
        *(float4*)&out[B_ * D_ + (size_t)b * T_ + t] = r;
    } else {
        float a = 0.f;
        const float* p = cp_g + (size_t)b * NBC_ * D_ + tid;
#pragma unroll 8
        for (int c2 = 0; c2 < NBC_; ++c2)
            a += p[(size_t)c2 * D_];
        out[b * D_ + tid] = a * invL;
    }
}

// ---------------- launch ----------------
extern "C" void kernel_launch(void* const* d_in, const int* in_sizes, int n_in,
                              void* d_out, int out_size, void* d_ws, size_t ws_size,
                              hipStream_t stream)
{
    const float* query = (const float*)d_in[0];
    const float* values = (const float*)d_in[1];
    const float* W1 = (const float*)d_in[2];
    const float* b1 = (const float*)d_in[3];
    const float* W2 = (const float*)d_in[4];
    const float* b2 = (const float*)d_in[5];
    const float* Vk = (const float*)d_in[6];
    // d_in[7] = V_bias: constant score shift, cancels in softmax.
    float* out = (float*)d_out;
    char* ws = (char*)d_ws;

    // ws layout (bytes), total 2,248,704
    float* scores = (float*)(ws + 0);                  // B*T*4        = 1048576
    float* hq     = (float*)(ws + 1048576);            // B*U*4        = 16384
    float* stats  = (float*)(ws + 1064960);            // B*32*4       = 4096
    float* ctxp   = (float*)(ws + 1069056);            // B*32*256*4   = 1048576
    unsigned short* W1h = (unsigned short*)(ws + 2117632);   // 65536
    unsigned short* W1l = (unsigned short*)(ws + 2183168);   // 65536

    prep<<<160, 256, 0, stream>>>(W1, query, W2, b2, W1h, W1l, hq);
    score_ctx<<<B_ * NBC_, 512, 0, stream>>>(values, W1h, W1l, hq, b1, Vk,
                                             scores, stats, ctxp);
    epilogue<<<288, 256, 0, stream>>>(scores, stats, ctxp, out);
}